// Round 6
// baseline (318.063 us; speedup 1.0000x reference)
//
#include <hip/hip_runtime.h>
#include <math.h>

#define NH 12
#define HD 32
#define GN 48
#define TK 96
#define NB 2
#define NN 1600
#define CC 384
#define BHN (NB*NH)          // 24
#define QKV_COLS (3*NH*HD)   // 1152
#define NQ (BHN*NN)          // 38400 total (b,h,n) queries

// ---------------------------------------------------------------------------
// GEMM: out = A[M,K] @ B[N,K]^T   (both row-major; B rows are output cols)
// MODE 0: scatter epilogue into q/k/v [B,h,N,d]   MODE 1: plain store [M,N]
// ---------------------------------------------------------------------------
template<int MODE>
__global__ __launch_bounds__(256)
void gemm_tile(const float* __restrict__ A, const float* __restrict__ B,
               float* __restrict__ o0, float* __restrict__ o1, float* __restrict__ o2,
               int M, int N, int K)
{
    __shared__ float As[16][64];
    __shared__ float Bs[16][64];
    const int tid = threadIdx.x;
    const int tx = tid & 15, ty = tid >> 4;
    const int m0 = blockIdx.y * 64, n0 = blockIdx.x * 64;
    const int lr = tid >> 2;          // tile row 0..63
    const int lc = (tid & 3) * 4;     // k-seg 0,4,8,12
    float acc[4][4] = {};

    for (int k0 = 0; k0 < K; k0 += 16) {
        float4 av = *(const float4*)&A[(m0 + lr) * K + k0 + lc];
        float4 bv = *(const float4*)&B[(n0 + lr) * K + k0 + lc];
        __syncthreads();   // previous iter's compute done before overwrite
        As[lc+0][lr] = av.x; As[lc+1][lr] = av.y; As[lc+2][lr] = av.z; As[lc+3][lr] = av.w;
        Bs[lc+0][lr] = bv.x; Bs[lc+1][lr] = bv.y; Bs[lc+2][lr] = bv.z; Bs[lc+3][lr] = bv.w;
        __syncthreads();
        #pragma unroll
        for (int kk = 0; kk < 16; ++kk) {
            float4 a4 = *(const float4*)&As[kk][ty*4];
            float4 b4 = *(const float4*)&Bs[kk][tx*4];
            float a[4] = {a4.x, a4.y, a4.z, a4.w};
            float b[4] = {b4.x, b4.y, b4.z, b4.w};
            #pragma unroll
            for (int i = 0; i < 4; ++i)
                #pragma unroll
                for (int j = 0; j < 4; ++j)
                    acc[i][j] = fmaf(a[i], b[j], acc[i][j]);
        }
    }

    if (MODE == 0) {
        #pragma unroll
        for (int i = 0; i < 4; ++i) {
            int row = m0 + ty*4 + i;
            int b  = row / NN;
            int nn = row - b * NN;
            #pragma unroll
            for (int j = 0; j < 4; ++j) {
                int col = n0 + tx*4 + j;
                int which = col / CC;          // uniform per tile (384 % 64 == 0)
                int rem = col - which * CC;
                int hh = rem >> 5, dd = rem & 31;
                float* dst = (which == 0) ? o0 : (which == 1) ? o1 : o2;
                dst[((b*NH + hh)*NN + nn)*HD + dd] = acc[i][j];
            }
        }
    } else {
        #pragma unroll
        for (int i = 0; i < 4; ++i) {
            int row = m0 + ty*4 + i;
            float4 st = make_float4(acc[i][0], acc[i][1], acc[i][2], acc[i][3]);
            *(float4*)&o0[row * N + n0 + tx*4] = st;
        }
    }
}

// ---------------------------------------------------------------------------
// Kernel 2: per-query group argmax (gidx), strict > == jnp.argmax tie-break
// ---------------------------------------------------------------------------
__global__ __launch_bounds__(256)
void group_route(const float* __restrict__ q, const float* __restrict__ wgp,
                 int* __restrict__ gidx)
{
    int t = blockIdx.x * 256 + threadIdx.x;   // [0, NQ)
    int bh = t / NN;
    int hh = bh % NH;
    const float* qp = q + t * HD;
    float qr[HD];
    #pragma unroll
    for (int i = 0; i < HD; i += 4) {
        float4 x = *(const float4*)&qp[i];
        qr[i] = x.x; qr[i+1] = x.y; qr[i+2] = x.z; qr[i+3] = x.w;
    }
    float best = -INFINITY; int bg = 0;
    for (int g = 0; g < GN; ++g) {
        const float* gp = wgp + hh*GN*HD + g*HD;
        float s = 0.f;
        #pragma unroll
        for (int i = 0; i < HD; i += 4) {
            float4 w = *(const float4*)&gp[i];
            s += qr[i]*w.x + qr[i+1]*w.y + qr[i+2]*w.z + qr[i+3]*w.w;
        }
        if (s > best) { best = s; bg = g; }
    }
    gidx[t] = bg;
}

// ---------------------------------------------------------------------------
// Kernel 3a: deterministic per-(bh,g) group-mean of q. One block per bh;
// 8 n-slices accumulate into private LDS partials, reduced in fixed order.
// ---------------------------------------------------------------------------
__global__ __launch_bounds__(256)
void qmean_all(const float* __restrict__ q, const int* __restrict__ gidx,
               float* __restrict__ qmean)
{
    __shared__ float part[8][GN][HD];   // 48 KB
    __shared__ int   cnt[8][GN];
    const int bh = blockIdx.x;
    const int tid = threadIdx.x;
    const int s = tid >> 5, dd = tid & 31;

    for (int i = tid; i < 8*GN*HD; i += 256) ((float*)part)[i] = 0.f;
    for (int i = tid; i < 8*GN; i += 256) ((int*)cnt)[i] = 0;
    __syncthreads();

    const int* __restrict__ gx = gidx + bh*NN;
    const float* __restrict__ qb = q + bh*NN*HD;
    for (int n = s; n < NN; n += 8) {
        int g = gx[n];                    // broadcast within the 32-lane slice
        part[s][g][dd] += qb[n*HD + dd];
        if (dd == 0) cnt[s][g]++;
    }
    __syncthreads();

    for (int idx = tid; idx < GN*HD; idx += 256) {
        int g = idx >> 5, d2 = idx & 31;
        float sum = 0.f; int ct = 0;
        #pragma unroll
        for (int ss = 0; ss < 8; ++ss) { sum += part[ss][g][d2]; ct += cnt[ss][g]; }
        qmean[(bh*GN + g)*HD + d2] = ct ? sum / (float)ct : 0.f;
    }
}

// ---------------------------------------------------------------------------
// Kernel 3b: scores[bh*GN+g][n] = qmean[bh,g] . k[bh,n]. Thread owns one n,
// k-row in registers, qmean tile in LDS (broadcast reads), coalesced stores.
// ---------------------------------------------------------------------------
__global__ __launch_bounds__(256)
void score_all(const float* __restrict__ qmean, const float* __restrict__ k,
               float* __restrict__ scores)
{
    __shared__ float Qs[GN][HD];          // 6 KB
    const int bh = blockIdx.y;
    const int tid = threadIdx.x;
    const int n = blockIdx.x*256 + tid;
    for (int i = tid; i < GN*HD; i += 256)
        ((float*)Qs)[i] = qmean[bh*GN*HD + i];
    __syncthreads();
    if (n >= NN) return;
    const float* __restrict__ kp = k + (bh*NN + n)*HD;
    float4 kr[8];
    #pragma unroll
    for (int c = 0; c < 8; ++c) kr[c] = *(const float4*)&kp[c*4];
    for (int g = 0; g < GN; ++g) {
        float s = 0.f;
        #pragma unroll
        for (int c = 0; c < 8; ++c) {
            float4 qv = *(const float4*)&Qs[g][c*4];   // same-addr broadcast
            s += kr[c].x*qv.x + kr[c].y*qv.y + kr[c].z*qv.z + kr[c].w*qv.w;
        }
        scores[(bh*GN + g)*NN + n] = s;               // coalesced per g
    }
}

// ---------------------------------------------------------------------------
// Kernel 3c: per-WAVE barrier-free radix top-96. Each 64-lane wave owns one
// (bh,g) row of 1600 scores: keys + 256-bin hist live in per-wave LDS slices
// (DS ops from a wave complete in program order -> no __syncthreads).
// Suffix-scan in registers via shfl; pivot via ballot; collect via ballot-
// compaction in ascending index order (== lax.top_k lowest-index ties).
// ---------------------------------------------------------------------------
__global__ __launch_bounds__(256)
void topk_radix(const float* __restrict__ scores, int* __restrict__ topk)
{
    __shared__ unsigned keysL[4][NN];     // 25.6 KB
    __shared__ unsigned histL[4][256];    // 4 KB
    const int tid = threadIdx.x;
    const int w = tid >> 6, lane = tid & 63;
    const int gid = blockIdx.x*4 + w;     // (bh*GN + g) in [0,1152)
    const float* __restrict__ row = scores + gid*NN;
    unsigned* keys = keysL[w];
    unsigned* hist = histL[w];

    // load + order-preserving transform (1600 = 25*64 exactly)
    #pragma unroll
    for (int i = 0; i < 25; ++i) {
        int m = lane + 64*i;
        unsigned u = __float_as_uint(row[m]);
        u = (u & 0x80000000u) ? ~u : (u | 0x80000000u);
        keys[m] = u;
    }

    unsigned prefix = 0, r = TK;
    #pragma unroll
    for (int pass = 0; pass < 4; ++pass) {
        const int shift = 24 - 8*pass;
        #pragma unroll
        for (int j = 0; j < 4; ++j) hist[lane*4 + j] = 0;
        #pragma unroll
        for (int i = 0; i < 25; ++i) {
            unsigned u = keys[lane + 64*i];
            bool match = (pass == 0) || ((u >> (shift+8)) == (prefix >> (shift+8)));
            if (match) atomicAdd(&hist[(u >> shift) & 255u], 1u);
        }
        // suffix scan: lane holds bins 4L..4L+3
        uint4 h = *(const uint4*)&hist[lane*4];
        unsigned s3 = h.w, s2 = h.z + s3, s1 = h.y + s2, s0 = h.x + s1;
        unsigned I = s0;                      // inclusive suffix over lane totals
        #pragma unroll
        for (int off = 1; off < 64; off <<= 1) {
            unsigned t = __shfl_down(I, off);
            if (lane + off < 64) I += t;
        }
        unsigned E = I - s0;                  // strict suffix (lanes > L)
        unsigned sf[5] = {E+s0, E+s1, E+s2, E+s3, E};
        int bj = -1; unsigned subc = 0;
        #pragma unroll
        for (int j = 0; j < 4; ++j)
            if (sf[j] >= r && sf[j+1] < r) { bj = j; subc = sf[j+1]; }
        unsigned long long mask = __ballot(bj >= 0);   // exactly one bit set
        int src = __ffsll(mask) - 1;
        int bstar = __shfl(lane*4 + bj, src);
        unsigned sub = (unsigned)__shfl((int)subc, src);
        prefix |= ((unsigned)bstar) << shift;
        r -= sub;
    }
    const unsigned P = prefix;   // exact 96th-largest key; r = #equals to take

    // collect: all keys > P, then first r keys == P (ascending index)
    int* tko = topk + gid*TK;
    int base = 0;
    #pragma unroll
    for (int i = 0; i < 25; ++i) {
        int m = lane + 64*i;
        bool gt = (keys[m] > P);
        unsigned long long mask = __ballot(gt);
        if (gt) tko[base + __popcll(mask & ((1ull << lane) - 1ull))] = m;
        base += (int)__popcll(mask);
    }
    #pragma unroll
    for (int i = 0; i < 25; ++i) {
        int m = lane + 64*i;
        bool eq = (keys[m] == P);
        unsigned long long mask = __ballot(eq);
        if (eq) {
            int pos = base + (int)__popcll(mask & ((1ull << lane) - 1ull));
            if (pos < TK) tko[pos] = m;
        }
        base += (int)__popcll(mask);
    }
}

// ---------------------------------------------------------------------------
// Kernel 4 (v4): 8 lanes/query, zero LDS/barriers, coalesced K reads
// (1 cache line per key per group), 3-step shfl dot reduce.
// ---------------------------------------------------------------------------
__global__ __launch_bounds__(256)
void sparse_attn4(const float* __restrict__ q, const float* __restrict__ k,
                  const float* __restrict__ v, const int* __restrict__ gidx,
                  const int* __restrict__ topk, float* __restrict__ out)
{
    const float scale = 0.17677669529663687f;   // 32^-0.5
    const int tid = threadIdx.x;
    const int qs = tid >> 3;              // query slot in block, 0..31
    const int dl = tid & 7;               // lane within query group, 0..7
    const int Q  = blockIdx.x * 32 + qs;  // [0, NQ)
    const int bh = Q / NN, nn = Q - bh * NN;
    const int lb = (tid & 63) & ~7;       // wave-lane base of this 8-lane group

    const int g = gidx[Q];
    const int* __restrict__ tk = topk + (bh*GN + g) * TK;
    const float* __restrict__ kb = k + bh * NN * HD;
    const float* __restrict__ vb = v + bh * NN * HD;

    float4 q4 = *(const float4*)&q[Q * HD + dl*4];

    int ki[12];
    #pragma unroll
    for (int t = 0; t < 12; ++t) ki[t] = tk[t*8 + dl];

    // phase 1: scores, one cache line per key per group
    float sc[12];
    #pragma unroll
    for (int t = 0; t < 12; ++t) {
        float keep = 0.f;
        #pragma unroll
        for (int u = 0; u < 8; ++u) {
            int kj = __shfl(ki[t], lb + u);
            float4 w = *(const float4*)&kb[kj*HD + dl*4];
            float p = fmaf(q4.x, w.x, fmaf(q4.y, w.y, fmaf(q4.z, w.z, q4.w*w.w)));
            p += __shfl_xor(p, 1);
            p += __shfl_xor(p, 2);
            p += __shfl_xor(p, 4);
            if (u == dl) keep = p;
        }
        sc[t] = keep * scale;
    }

    // softmax over the 96 scores (8-lane shfl reduce)
    float m = -INFINITY;
    #pragma unroll
    for (int t = 0; t < 12; ++t) m = fmaxf(m, sc[t]);
    #pragma unroll
    for (int off = 1; off < 8; off <<= 1) m = fmaxf(m, __shfl_xor(m, off));
    float l = 0.f;
    #pragma unroll
    for (int t = 0; t < 12; ++t) { sc[t] = __expf(sc[t] - m); l += sc[t]; }
    #pragma unroll
    for (int off = 1; off < 8; off <<= 1) l += __shfl_xor(l, off);
    float inv = 1.0f / l;
    #pragma unroll
    for (int t = 0; t < 12; ++t) sc[t] *= inv;

    // phase 2: weighted V gather; lane owns dims 4dl..4dl+3
    float a0 = 0.f, a1 = 0.f, a2 = 0.f, a3 = 0.f;
    #pragma unroll
    for (int t = 0; t < 12; ++t) {
        #pragma unroll
        for (int jj = 0; jj < 8; ++jj) {
            int   kj = __shfl(ki[t], lb + jj);
            float p  = __shfl(sc[t], lb + jj);
            float4 vv = *(const float4*)&vb[kj*HD + dl*4];
            a0 = fmaf(p, vv.x, a0);
            a1 = fmaf(p, vv.y, a1);
            a2 = fmaf(p, vv.z, a2);
            a3 = fmaf(p, vv.w, a3);
        }
    }

    const int b = bh / NH, hh = bh - b*NH;
    float* op = out + (b*NN + nn)*CC + hh*HD + dl*4;
    *(float4*)op = make_float4(a0, a1, a2, a3);
}

// ---------------------------------------------------------------------------
extern "C" void kernel_launch(void* const* d_in, const int* in_sizes, int n_in,
                              void* d_out, int out_size, void* d_ws, size_t ws_size,
                              hipStream_t stream)
{
    const float* x      = (const float*)d_in[0];   // [B,H,W,C] = [3200, 384]
    const float* w_qkv  = (const float*)d_in[1];   // [1152, 384]
    const float* w_gp   = (const float*)d_in[2];   // [48, 384] -> (12,48,32)
    const float* w_proj = (const float*)d_in[3];   // [384, 384]
    float* out = (float*)d_out;                    // [B,H,W,C]

    float* ws = (float*)d_ws;
    float* q        = ws;                 // [B,h,N,d] 1228800
    float* kk       = ws + 1228800;
    float* vv       = ws + 2457600;
    float* attn_out = ws + 3686400;       // [B,N,h*d] 1228800
    float* scores   = ws + 4915200;       // [1152][1600] 1843200
    float* qmean    = ws + 6758400;       // [1152][32]   36864
    int*   iws      = (int*)(ws + 6795264);
    int*   gidx     = iws;                // 38400
    int*   topk     = iws + 38400;        // 110592

    // 1) QKV projection, scatter into q/k/v
    gemm_tile<0><<<dim3(QKV_COLS/64, (NB*NN)/64), 256, 0, stream>>>(
        x, w_qkv, q, kk, vv, NB*NN, QKV_COLS, CC);

    // 2) query -> group routing
    group_route<<<NQ/256, 256, 0, stream>>>(q, w_gp, gidx);

    // 3a) deterministic group means
    qmean_all<<<BHN, 256, 0, stream>>>(q, gidx, qmean);

    // 3b) group->key score matrix
    score_all<<<dim3(7, BHN), 256, 0, stream>>>(qmean, kk, scores);

    // 3c) per-wave barrier-free radix top-96
    topk_radix<<<(BHN*GN)/4, 256, 0, stream>>>(scores, topk);

    // 4) sparse masked attention (coalesced two-phase)
    sparse_attn4<<<NQ/32, 256, 0, stream>>>(q, kk, vv, gidx, topk, attn_out);

    // 5) output projection
    gemm_tile<1><<<dim3(CC/64, (NB*NN)/64), 256, 0, stream>>>(
        attn_out, w_proj, out, nullptr, nullptr, NB*NN, CC, CC);
}

// Round 7
// 298.598 us; speedup vs baseline: 1.0652x; 1.0652x over previous
//
#include <hip/hip_runtime.h>
#include <math.h>

#define NH 12
#define HD 32
#define GN 48
#define TK 96
#define NB 2
#define NN 1600
#define CC 384
#define BHN (NB*NH)          // 24
#define QKV_COLS (3*NH*HD)   // 1152
#define NQ (BHN*NN)          // 38400 total (b,h,n) queries

// ---------------------------------------------------------------------------
// GEMM: out = A[M,K] @ B[N,K]^T   (both row-major; B rows are output cols)
// MODE 0: scatter epilogue into q/k/v [B,h,N,d]   MODE 1: plain store [M,N]
// ---------------------------------------------------------------------------
template<int MODE>
__global__ __launch_bounds__(256)
void gemm_tile(const float* __restrict__ A, const float* __restrict__ B,
               float* __restrict__ o0, float* __restrict__ o1, float* __restrict__ o2,
               int M, int N, int K)
{
    __shared__ float As[16][64];
    __shared__ float Bs[16][64];
    const int tid = threadIdx.x;
    const int tx = tid & 15, ty = tid >> 4;
    const int m0 = blockIdx.y * 64, n0 = blockIdx.x * 64;
    const int lr = tid >> 2;          // tile row 0..63
    const int lc = (tid & 3) * 4;     // k-seg 0,4,8,12
    float acc[4][4] = {};

    for (int k0 = 0; k0 < K; k0 += 16) {
        float4 av = *(const float4*)&A[(m0 + lr) * K + k0 + lc];
        float4 bv = *(const float4*)&B[(n0 + lr) * K + k0 + lc];
        __syncthreads();   // previous iter's compute done before overwrite
        As[lc+0][lr] = av.x; As[lc+1][lr] = av.y; As[lc+2][lr] = av.z; As[lc+3][lr] = av.w;
        Bs[lc+0][lr] = bv.x; Bs[lc+1][lr] = bv.y; Bs[lc+2][lr] = bv.z; Bs[lc+3][lr] = bv.w;
        __syncthreads();
        #pragma unroll
        for (int kk = 0; kk < 16; ++kk) {
            float4 a4 = *(const float4*)&As[kk][ty*4];
            float4 b4 = *(const float4*)&Bs[kk][tx*4];
            float a[4] = {a4.x, a4.y, a4.z, a4.w};
            float b[4] = {b4.x, b4.y, b4.z, b4.w};
            #pragma unroll
            for (int i = 0; i < 4; ++i)
                #pragma unroll
                for (int j = 0; j < 4; ++j)
                    acc[i][j] = fmaf(a[i], b[j], acc[i][j]);
        }
    }

    if (MODE == 0) {
        #pragma unroll
        for (int i = 0; i < 4; ++i) {
            int row = m0 + ty*4 + i;
            int b  = row / NN;
            int nn = row - b * NN;
            #pragma unroll
            for (int j = 0; j < 4; ++j) {
                int col = n0 + tx*4 + j;
                int which = col / CC;          // uniform per tile (384 % 64 == 0)
                int rem = col - which * CC;
                int hh = rem >> 5, dd = rem & 31;
                float* dst = (which == 0) ? o0 : (which == 1) ? o1 : o2;
                dst[((b*NH + hh)*NN + nn)*HD + dd] = acc[i][j];
            }
        }
    } else {
        #pragma unroll
        for (int i = 0; i < 4; ++i) {
            int row = m0 + ty*4 + i;
            float4 st = make_float4(acc[i][0], acc[i][1], acc[i][2], acc[i][3]);
            *(float4*)&o0[row * N + n0 + tx*4] = st;
        }
    }
}

// ---------------------------------------------------------------------------
// Kernel 2: per-query group argmax (gidx), strict > == jnp.argmax tie-break
// ---------------------------------------------------------------------------
__global__ __launch_bounds__(256)
void group_route(const float* __restrict__ q, const float* __restrict__ wgp,
                 int* __restrict__ gidx)
{
    int t = blockIdx.x * 256 + threadIdx.x;   // [0, NQ)
    int bh = t / NN;
    int hh = bh % NH;
    const float* qp = q + t * HD;
    float qr[HD];
    #pragma unroll
    for (int i = 0; i < HD; i += 4) {
        float4 x = *(const float4*)&qp[i];
        qr[i] = x.x; qr[i+1] = x.y; qr[i+2] = x.z; qr[i+3] = x.w;
    }
    float best = -INFINITY; int bg = 0;
    for (int g = 0; g < GN; ++g) {
        const float* gp = wgp + hh*GN*HD + g*HD;
        float s = 0.f;
        #pragma unroll
        for (int i = 0; i < HD; i += 4) {
            float4 w = *(const float4*)&gp[i];
            s += qr[i]*w.x + qr[i+1]*w.y + qr[i+2]*w.z + qr[i+3]*w.w;
        }
        if (s > best) { best = s; bg = g; }
    }
    gidx[t] = bg;
}

// ---------------------------------------------------------------------------
// Kernel 3a (v2): deterministic per-(bh,g) group-mean of q. One block per
// (bh,g) = 1152 blocks; 8 n-slices x 32 dims, REGISTER accumulation in the
// exact round-1 order (n = s, s+8, ... ; then slices s=0..7), LDS final
// reduce. No LDS RMW chain, chip fully occupied.
// ---------------------------------------------------------------------------
__global__ __launch_bounds__(256)
void qmean_all2(const float* __restrict__ q, const int* __restrict__ gidx,
                float* __restrict__ qmean)
{
    __shared__ float part[8][HD];
    __shared__ int   cnts[8];
    const int bid = blockIdx.x;       // bh*GN + g
    const int g = bid % GN, bh = bid / GN;
    const int tid = threadIdx.x;
    const int s = tid >> 5, dd = tid & 31;

    const int* __restrict__ gx = gidx + bh*NN;
    const float* __restrict__ qb = q + bh*NN*HD;

    float p = 0.f; int c = 0;
    for (int n = s; n < NN; n += 8) {
        if (gx[n] == g) { p += qb[n*HD + dd]; c++; }
    }
    part[s][dd] = p;
    if (dd == 0) cnts[s] = c;
    __syncthreads();
    if (tid < HD) {
        float sum = 0.f; int ct = 0;
        #pragma unroll
        for (int ss = 0; ss < 8; ++ss) { sum += part[ss][tid]; ct += cnts[ss]; }
        qmean[bid*HD + tid] = ct ? sum / (float)ct : 0.f;
    }
}

// ---------------------------------------------------------------------------
// Kernel 3b: scores[bh*GN+g][n] = qmean[bh,g] . k[bh,n]. Thread owns one n,
// k-row in registers, qmean tile in LDS (broadcast reads), coalesced stores.
// ---------------------------------------------------------------------------
__global__ __launch_bounds__(256)
void score_all(const float* __restrict__ qmean, const float* __restrict__ k,
               float* __restrict__ scores)
{
    __shared__ float Qs[GN][HD];          // 6 KB
    const int bh = blockIdx.y;
    const int tid = threadIdx.x;
    const int n = blockIdx.x*256 + tid;
    for (int i = tid; i < GN*HD; i += 256)
        ((float*)Qs)[i] = qmean[bh*GN*HD + i];
    __syncthreads();
    if (n >= NN) return;
    const float* __restrict__ kp = k + (bh*NN + n)*HD;
    float4 kr[8];
    #pragma unroll
    for (int c = 0; c < 8; ++c) kr[c] = *(const float4*)&kp[c*4];
    for (int g = 0; g < GN; ++g) {
        float s = 0.f;
        #pragma unroll
        for (int c = 0; c < 8; ++c) {
            float4 qv = *(const float4*)&Qs[g][c*4];   // same-addr broadcast
            s += kr[c].x*qv.x + kr[c].y*qv.y + kr[c].z*qv.z + kr[c].w*qv.w;
        }
        scores[(bh*GN + g)*NN + n] = s;               // coalesced per g
    }
}

// ---------------------------------------------------------------------------
// Kernel 3c: per-WAVE barrier-free radix top-96. Each 64-lane wave owns one
// (bh,g) row of 1600 scores: keys + 256-bin hist live in per-wave LDS slices
// (DS ops from a wave complete in program order -> no __syncthreads).
// Suffix-scan in registers via shfl; pivot via ballot; collect via ballot-
// compaction in ascending index order (== lax.top_k lowest-index ties).
// ---------------------------------------------------------------------------
__global__ __launch_bounds__(256)
void topk_radix(const float* __restrict__ scores, int* __restrict__ topk)
{
    __shared__ unsigned keysL[4][NN];     // 25.6 KB
    __shared__ unsigned histL[4][256];    // 4 KB
    const int tid = threadIdx.x;
    const int w = tid >> 6, lane = tid & 63;
    const int gid = blockIdx.x*4 + w;     // (bh*GN + g) in [0,1152)
    const float* __restrict__ row = scores + gid*NN;
    unsigned* keys = keysL[w];
    unsigned* hist = histL[w];

    // load + order-preserving transform (1600 = 25*64 exactly)
    #pragma unroll
    for (int i = 0; i < 25; ++i) {
        int m = lane + 64*i;
        unsigned u = __float_as_uint(row[m]);
        u = (u & 0x80000000u) ? ~u : (u | 0x80000000u);
        keys[m] = u;
    }

    unsigned prefix = 0, r = TK;
    #pragma unroll
    for (int pass = 0; pass < 4; ++pass) {
        const int shift = 24 - 8*pass;
        #pragma unroll
        for (int j = 0; j < 4; ++j) hist[lane*4 + j] = 0;
        #pragma unroll
        for (int i = 0; i < 25; ++i) {
            unsigned u = keys[lane + 64*i];
            bool match = (pass == 0) || ((u >> (shift+8)) == (prefix >> (shift+8)));
            if (match) atomicAdd(&hist[(u >> shift) & 255u], 1u);
        }
        // suffix scan: lane holds bins 4L..4L+3
        uint4 h = *(const uint4*)&hist[lane*4];
        unsigned s3 = h.w, s2 = h.z + s3, s1 = h.y + s2, s0 = h.x + s1;
        unsigned I = s0;                      // inclusive suffix over lane totals
        #pragma unroll
        for (int off = 1; off < 64; off <<= 1) {
            unsigned t = __shfl_down(I, off);
            if (lane + off < 64) I += t;
        }
        unsigned E = I - s0;                  // strict suffix (lanes > L)
        unsigned sf[5] = {E+s0, E+s1, E+s2, E+s3, E};
        int bj = -1; unsigned subc = 0;
        #pragma unroll
        for (int j = 0; j < 4; ++j)
            if (sf[j] >= r && sf[j+1] < r) { bj = j; subc = sf[j+1]; }
        unsigned long long mask = __ballot(bj >= 0);   // exactly one bit set
        int src = __ffsll(mask) - 1;
        int bstar = __shfl(lane*4 + bj, src);
        unsigned sub = (unsigned)__shfl((int)subc, src);
        prefix |= ((unsigned)bstar) << shift;
        r -= sub;
    }
    const unsigned P = prefix;   // exact 96th-largest key; r = #equals to take

    // collect: all keys > P, then first r keys == P (ascending index)
    int* tko = topk + gid*TK;
    int base = 0;
    #pragma unroll
    for (int i = 0; i < 25; ++i) {
        int m = lane + 64*i;
        bool gt = (keys[m] > P);
        unsigned long long mask = __ballot(gt);
        if (gt) tko[base + __popcll(mask & ((1ull << lane) - 1ull))] = m;
        base += (int)__popcll(mask);
    }
    #pragma unroll
    for (int i = 0; i < 25; ++i) {
        int m = lane + 64*i;
        bool eq = (keys[m] == P);
        unsigned long long mask = __ballot(eq);
        if (eq) {
            int pos = base + (int)__popcll(mask & ((1ull << lane) - 1ull));
            if (pos < TK) tko[pos] = m;
        }
        base += (int)__popcll(mask);
    }
}

// ---------------------------------------------------------------------------
// Kernel 4 (v4): 8 lanes/query, zero LDS/barriers, coalesced K reads
// (1 cache line per key per group), 3-step shfl dot reduce.
// ---------------------------------------------------------------------------
__global__ __launch_bounds__(256)
void sparse_attn4(const float* __restrict__ q, const float* __restrict__ k,
                  const float* __restrict__ v, const int* __restrict__ gidx,
                  const int* __restrict__ topk, float* __restrict__ out)
{
    const float scale = 0.17677669529663687f;   // 32^-0.5
    const int tid = threadIdx.x;
    const int qs = tid >> 3;              // query slot in block, 0..31
    const int dl = tid & 7;               // lane within query group, 0..7
    const int Q  = blockIdx.x * 32 + qs;  // [0, NQ)
    const int bh = Q / NN, nn = Q - bh * NN;
    const int lb = (tid & 63) & ~7;       // wave-lane base of this 8-lane group

    const int g = gidx[Q];
    const int* __restrict__ tk = topk + (bh*GN + g) * TK;
    const float* __restrict__ kb = k + bh * NN * HD;
    const float* __restrict__ vb = v + bh * NN * HD;

    float4 q4 = *(const float4*)&q[Q * HD + dl*4];

    int ki[12];
    #pragma unroll
    for (int t = 0; t < 12; ++t) ki[t] = tk[t*8 + dl];

    // phase 1: scores, one cache line per key per group
    float sc[12];
    #pragma unroll
    for (int t = 0; t < 12; ++t) {
        float keep = 0.f;
        #pragma unroll
        for (int u = 0; u < 8; ++u) {
            int kj = __shfl(ki[t], lb + u);
            float4 w = *(const float4*)&kb[kj*HD + dl*4];
            float p = fmaf(q4.x, w.x, fmaf(q4.y, w.y, fmaf(q4.z, w.z, q4.w*w.w)));
            p += __shfl_xor(p, 1);
            p += __shfl_xor(p, 2);
            p += __shfl_xor(p, 4);
            if (u == dl) keep = p;
        }
        sc[t] = keep * scale;
    }

    // softmax over the 96 scores (8-lane shfl reduce)
    float m = -INFINITY;
    #pragma unroll
    for (int t = 0; t < 12; ++t) m = fmaxf(m, sc[t]);
    #pragma unroll
    for (int off = 1; off < 8; off <<= 1) m = fmaxf(m, __shfl_xor(m, off));
    float l = 0.f;
    #pragma unroll
    for (int t = 0; t < 12; ++t) { sc[t] = __expf(sc[t] - m); l += sc[t]; }
    #pragma unroll
    for (int off = 1; off < 8; off <<= 1) l += __shfl_xor(l, off);
    float inv = 1.0f / l;
    #pragma unroll
    for (int t = 0; t < 12; ++t) sc[t] *= inv;

    // phase 2: weighted V gather; lane owns dims 4dl..4dl+3
    float a0 = 0.f, a1 = 0.f, a2 = 0.f, a3 = 0.f;
    #pragma unroll
    for (int t = 0; t < 12; ++t) {
        #pragma unroll
        for (int jj = 0; jj < 8; ++jj) {
            int   kj = __shfl(ki[t], lb + jj);
            float p  = __shfl(sc[t], lb + jj);
            float4 vv = *(const float4*)&vb[kj*HD + dl*4];
            a0 = fmaf(p, vv.x, a0);
            a1 = fmaf(p, vv.y, a1);
            a2 = fmaf(p, vv.z, a2);
            a3 = fmaf(p, vv.w, a3);
        }
    }

    const int b = bh / NH, hh = bh - b*NH;
    float* op = out + (b*NN + nn)*CC + hh*HD + dl*4;
    *(float4*)op = make_float4(a0, a1, a2, a3);
}

// ---------------------------------------------------------------------------
extern "C" void kernel_launch(void* const* d_in, const int* in_sizes, int n_in,
                              void* d_out, int out_size, void* d_ws, size_t ws_size,
                              hipStream_t stream)
{
    const float* x      = (const float*)d_in[0];   // [B,H,W,C] = [3200, 384]
    const float* w_qkv  = (const float*)d_in[1];   // [1152, 384]
    const float* w_gp   = (const float*)d_in[2];   // [48, 384] -> (12,48,32)
    const float* w_proj = (const float*)d_in[3];   // [384, 384]
    float* out = (float*)d_out;                    // [B,H,W,C]

    float* ws = (float*)d_ws;
    float* q        = ws;                 // [B,h,N,d] 1228800
    float* kk       = ws + 1228800;
    float* vv       = ws + 2457600;
    float* attn_out = ws + 3686400;       // [B,N,h*d] 1228800
    float* scores   = ws + 4915200;       // [1152][1600] 1843200
    float* qmean    = ws + 6758400;       // [1152][32]   36864
    int*   iws      = (int*)(ws + 6795264);
    int*   gidx     = iws;                // 38400
    int*   topk     = iws + 38400;        // 110592

    // 1) QKV projection, scatter into q/k/v
    gemm_tile<0><<<dim3(QKV_COLS/64, (NB*NN)/64), 256, 0, stream>>>(
        x, w_qkv, q, kk, vv, NB*NN, QKV_COLS, CC);

    // 2) query -> group routing
    group_route<<<NQ/256, 256, 0, stream>>>(q, w_gp, gidx);

    // 3a) deterministic group means (register accumulation, 1152 blocks)
    qmean_all2<<<BHN*GN, 256, 0, stream>>>(q, gidx, qmean);

    // 3b) group->key score matrix
    score_all<<<dim3(7, BHN), 256, 0, stream>>>(qmean, kk, scores);

    // 3c) per-wave barrier-free radix top-96
    topk_radix<<<(BHN*GN)/4, 256, 0, stream>>>(scores, topk);

    // 4) sparse masked attention (coalesced two-phase)
    sparse_attn4<<<NQ/32, 256, 0, stream>>>(q, kk, vv, gidx, topk, attn_out);

    // 5) output projection
    gemm_tile<1><<<dim3(CC/64, (NB*NN)/64), 256, 0, stream>>>(
        attn_out, w_proj, out, nullptr, nullptr, NB*NN, CC, CC);
}